// Round 1
// baseline (4111.097 us; speedup 1.0000x reference)
//
#include <hip/hip_runtime.h>
#include <hip/hip_bf16.h>

// Problem constants
#define NBANDS 5
#define BATCH  512
#define KQN    64     // queries per sample
#define DM     200    // model dim
#define NHEAD  4
#define HD     50     // head dim
#define HIDW   512    // router hidden
#define TKV    320    // NBANDS*KQN keys
#define FIN    64000  // NBANDS*KQN*DM
#define KSPLIT 8
#define KCH    8000   // FIN/KSPLIT

// flat[b, ki] = bands[ki/12800, b, (ki%12800)/200, ki%200]
//            -> linear bands index: b*12800 + ki + (ki/12800)*6540800

// ---------------------------------------------------------------------------
// K1: router GEMM partials: part[z][b][j] = sum_{ki in chunk z} flat[b,ki]*w1[j,ki]
// fp32 (precision-critical: argmax flips if done in bf16). 64x64 tile, 4x4/thread.
// ---------------------------------------------------------------------------
__global__ __launch_bounds__(256) void k_router_gemm(
    const float* __restrict__ bands, const float* __restrict__ w1,
    float* __restrict__ part)
{
    __shared__ float As[16][68];
    __shared__ float Bs[16][68];
    const int j0 = blockIdx.x * 64;
    const int b0 = blockIdx.y * 64;
    const int z  = blockIdx.z;
    const int t  = threadIdx.x;
    const int tx = t & 15, ty = t >> 4;
    const int lm = t >> 2;          // 0..63 (row within tile for loading)
    const int lk = (t & 3) << 2;    // 0,4,8,12
    float acc[4][4] = {};
    const int kbase = z * KCH;
    for (int ks = 0; ks < KCH; ks += 16) {
        const int ki   = kbase + ks + lk;
        const int band = ki / 12800;   // aligned 4-groups never cross a band
        const float4 a4 = *(const float4*)(bands + (size_t)(b0 + lm) * 12800 + ki
                                           + (size_t)band * 6540800);
        const float4 b4 = *(const float4*)(w1 + (size_t)(j0 + lm) * FIN + ki);
        __syncthreads();   // previous compute done before LDS overwrite
        As[lk + 0][lm] = a4.x; As[lk + 1][lm] = a4.y;
        As[lk + 2][lm] = a4.z; As[lk + 3][lm] = a4.w;
        Bs[lk + 0][lm] = b4.x; Bs[lk + 1][lm] = b4.y;
        Bs[lk + 2][lm] = b4.z; Bs[lk + 3][lm] = b4.w;
        __syncthreads();
#pragma unroll
        for (int kk = 0; kk < 16; ++kk) {
            const float4 av = *(const float4*)&As[kk][ty << 2];
            const float4 bv = *(const float4*)&Bs[kk][tx << 2];
            const float a_[4] = {av.x, av.y, av.z, av.w};
            const float b_[4] = {bv.x, bv.y, bv.z, bv.w};
#pragma unroll
            for (int i = 0; i < 4; ++i)
#pragma unroll
                for (int j = 0; j < 4; ++j)
                    acc[i][j] = fmaf(a_[i], b_[j], acc[i][j]);
        }
    }
    float* po = part + (size_t)z * (BATCH * HIDW);
#pragma unroll
    for (int i = 0; i < 4; ++i) {
        const int bb = b0 + (ty << 2) + i;
#pragma unroll
        for (int j = 0; j < 4; ++j)
            po[bb * HIDW + j0 + (tx << 2) + j] = acc[i][j];
    }
}

// ---------------------------------------------------------------------------
// K2: h = relu(sum_z part + b1)
// ---------------------------------------------------------------------------
__global__ __launch_bounds__(256) void k_reduce_relu(
    const float* __restrict__ part, const float* __restrict__ b1,
    float* __restrict__ h)
{
    const int tid = blockIdx.x * 256 + threadIdx.x;  // < BATCH*HIDW
    float s = b1[tid & (HIDW - 1)];
#pragma unroll
    for (int z = 0; z < KSPLIT; ++z) s += part[z * (BATCH * HIDW) + tid];
    h[tid] = fmaxf(s, 0.f);
}

// ---------------------------------------------------------------------------
// K3: logits = h @ w2^T + b2 ; sel = argmax (softmax is monotonic -> skip it)
// First-max tie rule matches jnp.argmax.
// ---------------------------------------------------------------------------
__global__ __launch_bounds__(256) void k_argmax(
    const float* __restrict__ h, const float* __restrict__ w2,
    const float* __restrict__ b2, int* __restrict__ sel)
{
    __shared__ float red[NBANDS][256];
    const int b = blockIdx.x, t = threadIdx.x;
    float acc[NBANDS] = {0.f, 0.f, 0.f, 0.f, 0.f};
    for (int j = t; j < HIDW; j += 256) {
        const float hv = h[b * HIDW + j];
#pragma unroll
        for (int n = 0; n < NBANDS; ++n)
            acc[n] = fmaf(hv, w2[n * HIDW + j], acc[n]);
    }
#pragma unroll
    for (int n = 0; n < NBANDS; ++n) red[n][t] = acc[n];
    __syncthreads();
    for (int s = 128; s > 0; s >>= 1) {
        if (t < s) {
#pragma unroll
            for (int n = 0; n < NBANDS; ++n) red[n][t] += red[n][t + s];
        }
        __syncthreads();
    }
    if (t == 0) {
        int best = 0;
        float bv = red[0][0] + b2[0];
        for (int n = 1; n < NBANDS; ++n) {
            const float v = red[n][0] + b2[n];
            if (v > bv) { bv = v; best = n; }
        }
        sel[b] = best;
    }
}

// ---------------------------------------------------------------------------
// K4: q projection for the selected band: q[b,r,:] = bands[sel[b],b,r,:] @ wq^T + bq
// One block per b; 64 rows staged in LDS; thread (r,c) does rows r,r+32, outs c::8.
// ---------------------------------------------------------------------------
__global__ __launch_bounds__(256) void k_qproj(
    const float* __restrict__ bands, const int* __restrict__ sel,
    const float* __restrict__ ipw, const float* __restrict__ ipb,
    float* __restrict__ q)
{
    __shared__ float xs[64][204];
    const int b = blockIdx.x;
    const int t = threadIdx.x;
    const int band = sel[b];
    for (int idx = t; idx < KQN * DM; idx += 256) {
        const int r = idx / DM, col = idx - r * DM;
        xs[r][col] = bands[(size_t)((band * BATCH + b) * KQN + r) * DM + col];
    }
    __syncthreads();
    const int r = t & 31, c = t >> 5;
    for (int oo = c; oo < DM; oo += 8) {
        const float* wrow = ipw + (size_t)oo * DM;   // wq rows 0..199
        const float bias = ipb[oo];
        float4 s0 = {0, 0, 0, 0}, s1 = {0, 0, 0, 0};
        for (int in = 0; in < DM; in += 4) {
            const float4 w4 = *(const float4*)(wrow + in);
            const float4 x0 = *(const float4*)&xs[r][in];
            const float4 x1 = *(const float4*)&xs[r + 32][in];
            s0.x = fmaf(x0.x, w4.x, s0.x); s0.y = fmaf(x0.y, w4.y, s0.y);
            s0.z = fmaf(x0.z, w4.z, s0.z); s0.w = fmaf(x0.w, w4.w, s0.w);
            s1.x = fmaf(x1.x, w4.x, s1.x); s1.y = fmaf(x1.y, w4.y, s1.y);
            s1.z = fmaf(x1.z, w4.z, s1.z); s1.w = fmaf(x1.w, w4.w, s1.w);
        }
        const float a0 = bias + ((s0.x + s0.y) + (s0.z + s0.w));
        const float a1 = bias + ((s1.x + s1.y) + (s1.z + s1.w));
        q[(size_t)(b * KQN + r) * DM + oo] = a0;
        q[(size_t)(b * KQN + r + 32) * DM + oo] = a1;
    }
}

// ---------------------------------------------------------------------------
// K5: K/V projections over all 512*320 kv rows -> bf16 (storage precision is ample)
// ---------------------------------------------------------------------------
__global__ __launch_bounds__(256) void k_kvproj(
    const float* __restrict__ bands, const float* __restrict__ ipw,
    const float* __restrict__ ipb, __hip_bfloat16* __restrict__ Kp,
    __hip_bfloat16* __restrict__ Vp)
{
    __shared__ float xs[64][204];
    const int g0 = blockIdx.x * 64;       // global kv row = b*320 + tk
    const int t = threadIdx.x;
    for (int idx = t; idx < 64 * DM; idx += 256) {
        const int r = idx / DM, col = idx - r * DM;
        const int gg = g0 + r;
        const int bb = gg / TKV, tk = gg - bb * TKV;
        const int band = tk >> 6, kk = tk & 63;
        xs[r][col] = bands[(size_t)(((band * BATCH + bb) * KQN) + kk) * DM + col];
    }
    __syncthreads();
    const int r = t & 31, c = t >> 5;
    for (int oo = c; oo < 2 * DM; oo += 8) {   // 0..199 -> K, 200..399 -> V
        const float* wrow = ipw + (size_t)(DM + oo) * DM;  // wk rows 200.., wv rows 400..
        const float bias = ipb[DM + oo];
        float4 s0 = {0, 0, 0, 0}, s1 = {0, 0, 0, 0};
        for (int in = 0; in < DM; in += 4) {
            const float4 w4 = *(const float4*)(wrow + in);
            const float4 x0 = *(const float4*)&xs[r][in];
            const float4 x1 = *(const float4*)&xs[r + 32][in];
            s0.x = fmaf(x0.x, w4.x, s0.x); s0.y = fmaf(x0.y, w4.y, s0.y);
            s0.z = fmaf(x0.z, w4.z, s0.z); s0.w = fmaf(x0.w, w4.w, s0.w);
            s1.x = fmaf(x1.x, w4.x, s1.x); s1.y = fmaf(x1.y, w4.y, s1.y);
            s1.z = fmaf(x1.z, w4.z, s1.z); s1.w = fmaf(x1.w, w4.w, s1.w);
        }
        const float a0 = bias + ((s0.x + s0.y) + (s0.z + s0.w));
        const float a1 = bias + ((s1.x + s1.y) + (s1.z + s1.w));
        const size_t gr0 = (size_t)(g0 + r) * DM, gr1 = (size_t)(g0 + r + 32) * DM;
        if (oo < DM) {
            Kp[gr0 + oo] = __float2bfloat16(a0);
            Kp[gr1 + oo] = __float2bfloat16(a1);
        } else {
            Vp[gr0 + (oo - DM)] = __float2bfloat16(a0);
            Vp[gr1 + (oo - DM)] = __float2bfloat16(a1);
        }
    }
}

// ---------------------------------------------------------------------------
// K6: attention per (b, head). Full 320-key scores in LDS (fp32), softmax,
// then PV. LDS = 66.5K (K/V tile) + 83K (scores) + aux = 151.5K <= 160K.
// ---------------------------------------------------------------------------
__global__ __launch_bounds__(256) void k_attn(
    const float* __restrict__ qbuf, const __hip_bfloat16* __restrict__ Kp,
    const __hip_bfloat16* __restrict__ Vp, float* __restrict__ obuf)
{
    __shared__ float Ks[TKV][52];     // K tile, later reused for V
    __shared__ float sc[KQN][324];    // scores -> probabilities
    __shared__ float m4[KQN][4];
    __shared__ float l4[KQN][4];
    const int b = blockIdx.x, hh = blockIdx.y;
    const int t = threadIdx.x;
    const int qq = t & 63, g = t >> 6;     // g is wave-uniform -> no divergence

    for (int idx = t; idx < TKV * HD; idx += 256) {
        const int key = idx / HD, e = idx - key * HD;
        Ks[key][e] = __bfloat162float(Kp[(size_t)(b * TKV + key) * DM + hh * HD + e]);
    }
    float qreg[HD];
    {
        const float* qp = qbuf + (size_t)(b * KQN + qq) * DM + hh * HD;
#pragma unroll
        for (int e = 0; e < HD; ++e) qreg[e] = qp[e];
    }
    __syncthreads();

    const float scale = 0.14142135623730951f;  // 1/sqrt(50)
    float mloc = -1e30f;
    for (int key = g; key < TKV; key += 4) {
        float4 s4 = {0, 0, 0, 0};
#pragma unroll
        for (int e4 = 0; e4 < 48; e4 += 4) {
            const float4 k4 = *(const float4*)&Ks[key][e4];
            s4.x = fmaf(qreg[e4 + 0], k4.x, s4.x);
            s4.y = fmaf(qreg[e4 + 1], k4.y, s4.y);
            s4.z = fmaf(qreg[e4 + 2], k4.z, s4.z);
            s4.w = fmaf(qreg[e4 + 3], k4.w, s4.w);
        }
        float s = (s4.x + s4.y) + (s4.z + s4.w);
        s = fmaf(qreg[48], Ks[key][48], s);
        s = fmaf(qreg[49], Ks[key][49], s);
        s *= scale;
        sc[qq][key] = s;
        mloc = fmaxf(mloc, s);
    }
    m4[qq][g] = mloc;
    __syncthreads();                       // scores done; Ks now dead
    const float m = fmaxf(fmaxf(m4[qq][0], m4[qq][1]), fmaxf(m4[qq][2], m4[qq][3]));
    float lloc = 0.f;
    for (int key = g; key < TKV; key += 4) {
        const float p = __expf(sc[qq][key] - m);
        sc[qq][key] = p;
        lloc += p;
    }
    l4[qq][g] = lloc;
    for (int idx = t; idx < TKV * HD; idx += 256) {   // overlap V load with softmax
        const int key = idx / HD, e = idx - key * HD;
        Ks[key][e] = __bfloat162float(Vp[(size_t)(b * TKV + key) * DM + hh * HD + e]);
    }
    __syncthreads();

    const float l = (l4[qq][0] + l4[qq][1]) + (l4[qq][2] + l4[qq][3]);
    const float inv = 1.f / l;
    float acc[13];
#pragma unroll
    for (int i = 0; i < 13; ++i) acc[i] = 0.f;
    for (int key = 0; key < TKV; ++key) {
        const float p = sc[qq][key];
#pragma unroll
        for (int i = 0; i < 13; ++i) {
            const int e = g + (i << 2);
            if (e < HD) acc[i] = fmaf(p, Ks[key][e], acc[i]);
        }
    }
    float* op = obuf + (size_t)(b * KQN + qq) * DM + hh * HD;
#pragma unroll
    for (int i = 0; i < 13; ++i) {
        const int e = g + (i << 2);
        if (e < HD) op[e] = acc[i] * inv;
    }
}

// ---------------------------------------------------------------------------
// K7: out = o @ out_w^T + out_b
// ---------------------------------------------------------------------------
__global__ __launch_bounds__(256) void k_outproj(
    const float* __restrict__ obuf, const float* __restrict__ outw,
    const float* __restrict__ outb, float* __restrict__ out)
{
    __shared__ float xs[64][204];
    const int b = blockIdx.x;
    const int t = threadIdx.x;
    for (int idx = t; idx < KQN * DM; idx += 256) {
        const int r = idx / DM, col = idx - r * DM;
        xs[r][col] = obuf[(size_t)(b * KQN + r) * DM + col];
    }
    __syncthreads();
    const int r = t & 31, c = t >> 5;
    for (int oo = c; oo < DM; oo += 8) {
        const float* wrow = outw + (size_t)oo * DM;
        const float bias = outb[oo];
        float4 s0 = {0, 0, 0, 0}, s1 = {0, 0, 0, 0};
        for (int in = 0; in < DM; in += 4) {
            const float4 w4 = *(const float4*)(wrow + in);
            const float4 x0 = *(const float4*)&xs[r][in];
            const float4 x1 = *(const float4*)&xs[r + 32][in];
            s0.x = fmaf(x0.x, w4.x, s0.x); s0.y = fmaf(x0.y, w4.y, s0.y);
            s0.z = fmaf(x0.z, w4.z, s0.z); s0.w = fmaf(x0.w, w4.w, s0.w);
            s1.x = fmaf(x1.x, w4.x, s1.x); s1.y = fmaf(x1.y, w4.y, s1.y);
            s1.z = fmaf(x1.z, w4.z, s1.z); s1.w = fmaf(x1.w, w4.w, s1.w);
        }
        const float a0 = bias + ((s0.x + s0.y) + (s0.z + s0.w));
        const float a1 = bias + ((s1.x + s1.y) + (s1.z + s1.w));
        out[(size_t)(b * KQN + r) * DM + oo] = a0;
        out[(size_t)(b * KQN + r + 32) * DM + oo] = a1;
    }
}

// ---------------------------------------------------------------------------
// Workspace layout (bytes):
//   part  fp32 [8][512][512]      @ 0          ( 8,388,608)
//   h     fp32 [512][512]         @ 8388608    ( 1,048,576)
//   sel   int  [512]              @ 9437184    (     2,048)
//   q     fp32 [512][64][200]     @ 9439232    (26,214,400)
//   Kp    bf16 [512][320][200]    @ 35653632   (65,536,000)
//   Vp    bf16 [512][320][200]    @ 101189632  (65,536,000)
//   obuf  fp32 [512][64][200]     @ 166725632  (26,214,400)
//   total 192,940,032 bytes
// ---------------------------------------------------------------------------
extern "C" void kernel_launch(void* const* d_in, const int* in_sizes, int n_in,
                              void* d_out, int out_size, void* d_ws, size_t ws_size,
                              hipStream_t stream)
{
    const float* bands = (const float*)d_in[0];
    const float* w1    = (const float*)d_in[1];
    const float* b1    = (const float*)d_in[2];
    const float* w2    = (const float*)d_in[3];
    const float* b2    = (const float*)d_in[4];
    const float* ipw   = (const float*)d_in[5];
    const float* ipb   = (const float*)d_in[6];
    const float* outw  = (const float*)d_in[7];
    const float* outb  = (const float*)d_in[8];
    float* out = (float*)d_out;

    if (ws_size < (size_t)192940032) return;  // layout needs 193 MB scratch

    char* ws = (char*)d_ws;
    float* part = (float*)(ws + 0);
    float* h    = (float*)(ws + 8388608);
    int*   sel  = (int*)  (ws + 9437184);
    float* q    = (float*)(ws + 9439232);
    __hip_bfloat16* Kp = (__hip_bfloat16*)(ws + 35653632);
    __hip_bfloat16* Vp = (__hip_bfloat16*)(ws + 101189632);
    float* obuf = (float*)(ws + 166725632);

    k_router_gemm<<<dim3(8, 8, KSPLIT), 256, 0, stream>>>(bands, w1, part);
    k_reduce_relu<<<(BATCH * HIDW) / 256, 256, 0, stream>>>(part, b1, h);
    k_argmax<<<BATCH, 256, 0, stream>>>(h, w2, b2, sel);
    k_qproj<<<BATCH, 256, 0, stream>>>(bands, sel, ipw, ipb, q);
    k_kvproj<<<(BATCH * TKV) / 64, 256, 0, stream>>>(bands, ipw, ipb, Kp, Vp);
    k_attn<<<dim3(BATCH, NHEAD), 256, 0, stream>>>(q, Kp, Vp, obuf);
    k_outproj<<<BATCH, 256, 0, stream>>>(obuf, outw, outb, out);
}

// Round 2
// 2573.786 us; speedup vs baseline: 1.5973x; 1.5973x over previous
//
#include <hip/hip_runtime.h>
#include <hip/hip_bf16.h>

// Problem constants
#define NBANDS 5
#define BATCH  512
#define KQN    64     // queries per sample
#define DM     200    // model dim
#define NHEAD  4
#define HD     50     // head dim
#define HIDW   512    // router hidden
#define TKV    320    // NBANDS*KQN keys
#define FIN    64000  // NBANDS*KQN*DM
#define KSPLIT 8
#define KCH    8000   // FIN/KSPLIT
#define KPAD   232    // padded K for bf16 LDS tiles (200 data + zeros; 232*2B=464B=29*16B)

typedef __bf16  bf16x8 __attribute__((ext_vector_type(8)));
typedef float   f32x4  __attribute__((ext_vector_type(4)));

static __device__ inline unsigned short f2bf(float f) {
    __hip_bfloat16 h = __float2bfloat16(f);
    return *reinterpret_cast<unsigned short*>(&h);
}

// ---------------------------------------------------------------------------
// K1: router GEMM partials: part[z][b][j] = sum_{ki in chunk z} flat[b,ki]*w1[j,ki]
// fp32 (precision-critical: argmax flips if done in bf16). 64x64 tile, 4x4/thread.
// ---------------------------------------------------------------------------
__global__ __launch_bounds__(256) void k_router_gemm(
    const float* __restrict__ bands, const float* __restrict__ w1,
    float* __restrict__ part)
{
    __shared__ float As[16][68];
    __shared__ float Bs[16][68];
    const int j0 = blockIdx.x * 64;
    const int b0 = blockIdx.y * 64;
    const int z  = blockIdx.z;
    const int t  = threadIdx.x;
    const int tx = t & 15, ty = t >> 4;
    const int lm = t >> 2;          // 0..63 (row within tile for loading)
    const int lk = (t & 3) << 2;    // 0,4,8,12
    float acc[4][4] = {};
    const int kbase = z * KCH;
    for (int ks = 0; ks < KCH; ks += 16) {
        const int ki   = kbase + ks + lk;
        const int band = ki / 12800;   // aligned 4-groups never cross a band
        const float4 a4 = *(const float4*)(bands + (size_t)(b0 + lm) * 12800 + ki
                                           + (size_t)band * 6540800);
        const float4 b4 = *(const float4*)(w1 + (size_t)(j0 + lm) * FIN + ki);
        __syncthreads();   // previous compute done before LDS overwrite
        As[lk + 0][lm] = a4.x; As[lk + 1][lm] = a4.y;
        As[lk + 2][lm] = a4.z; As[lk + 3][lm] = a4.w;
        Bs[lk + 0][lm] = b4.x; Bs[lk + 1][lm] = b4.y;
        Bs[lk + 2][lm] = b4.z; Bs[lk + 3][lm] = b4.w;
        __syncthreads();
#pragma unroll
        for (int kk = 0; kk < 16; ++kk) {
            const float4 av = *(const float4*)&As[kk][ty << 2];
            const float4 bv = *(const float4*)&Bs[kk][tx << 2];
            const float a_[4] = {av.x, av.y, av.z, av.w};
            const float b_[4] = {bv.x, bv.y, bv.z, bv.w};
#pragma unroll
            for (int i = 0; i < 4; ++i)
#pragma unroll
                for (int j = 0; j < 4; ++j)
                    acc[i][j] = fmaf(a_[i], b_[j], acc[i][j]);
        }
    }
    float* po = part + (size_t)z * (BATCH * HIDW);
#pragma unroll
    for (int i = 0; i < 4; ++i) {
        const int bb = b0 + (ty << 2) + i;
#pragma unroll
        for (int j = 0; j < 4; ++j)
            po[bb * HIDW + j0 + (tx << 2) + j] = acc[i][j];
    }
}

// ---------------------------------------------------------------------------
// K2: h = relu(sum_z part + b1)
// ---------------------------------------------------------------------------
__global__ __launch_bounds__(256) void k_reduce_relu(
    const float* __restrict__ part, const float* __restrict__ b1,
    float* __restrict__ h)
{
    const int tid = blockIdx.x * 256 + threadIdx.x;  // < BATCH*HIDW
    float s = b1[tid & (HIDW - 1)];
#pragma unroll
    for (int z = 0; z < KSPLIT; ++z) s += part[z * (BATCH * HIDW) + tid];
    h[tid] = fmaxf(s, 0.f);
}

// ---------------------------------------------------------------------------
// K2b: pre-convert in_proj rows 200..599 (wk|wv) to bf16, K padded to 232 with
// zeros. Wb[j][c] = bf16(ipw[200+j][c]). Reused by all 12800 kvproj blocks.
// ---------------------------------------------------------------------------
__global__ __launch_bounds__(256) void k_wprep(
    const float* __restrict__ ipw, unsigned short* __restrict__ Wb)
{
    const int j = blockIdx.x;        // 0..399
    const int c = threadIdx.x;       // 0..255 (232 active)
    if (c < KPAD) {
        const float v = (c < DM) ? ipw[(size_t)(DM + j) * DM + c] : 0.f;
        Wb[(size_t)j * KPAD + c] = f2bf(v);
    }
}

// ---------------------------------------------------------------------------
// K3: logits = h @ w2^T + b2 ; sel = argmax (softmax is monotonic -> skip it)
// ---------------------------------------------------------------------------
__global__ __launch_bounds__(256) void k_argmax(
    const float* __restrict__ h, const float* __restrict__ w2,
    const float* __restrict__ b2, int* __restrict__ sel)
{
    __shared__ float red[NBANDS][256];
    const int b = blockIdx.x, t = threadIdx.x;
    float acc[NBANDS] = {0.f, 0.f, 0.f, 0.f, 0.f};
    for (int j = t; j < HIDW; j += 256) {
        const float hv = h[b * HIDW + j];
#pragma unroll
        for (int n = 0; n < NBANDS; ++n)
            acc[n] = fmaf(hv, w2[n * HIDW + j], acc[n]);
    }
#pragma unroll
    for (int n = 0; n < NBANDS; ++n) red[n][t] = acc[n];
    __syncthreads();
    for (int s = 128; s > 0; s >>= 1) {
        if (t < s) {
#pragma unroll
            for (int n = 0; n < NBANDS; ++n) red[n][t] += red[n][t + s];
        }
        __syncthreads();
    }
    if (t == 0) {
        int best = 0;
        float bv = red[0][0] + b2[0];
        for (int n = 1; n < NBANDS; ++n) {
            const float v = red[n][0] + b2[n];
            if (v > bv) { bv = v; best = n; }
        }
        sel[b] = best;
    }
}

// ---------------------------------------------------------------------------
// K4: q projection for the selected band (fp32 — feeds scores, keep precise)
// ---------------------------------------------------------------------------
__global__ __launch_bounds__(256) void k_qproj(
    const float* __restrict__ bands, const int* __restrict__ sel,
    const float* __restrict__ ipw, const float* __restrict__ ipb,
    float* __restrict__ q)
{
    __shared__ float xs[64][204];
    const int b = blockIdx.x;
    const int t = threadIdx.x;
    const int band = sel[b];
    for (int idx = t; idx < KQN * DM; idx += 256) {
        const int r = idx / DM, col = idx - r * DM;
        xs[r][col] = bands[(size_t)((band * BATCH + b) * KQN + r) * DM + col];
    }
    __syncthreads();
    const int r = t & 31, c = t >> 5;
    for (int oo = c; oo < DM; oo += 8) {
        const float* wrow = ipw + (size_t)oo * DM;   // wq rows 0..199
        const float bias = ipb[oo];
        float4 s0 = {0, 0, 0, 0}, s1 = {0, 0, 0, 0};
        for (int in = 0; in < DM; in += 4) {
            const float4 w4 = *(const float4*)(wrow + in);
            const float4 x0 = *(const float4*)&xs[r][in];
            const float4 x1 = *(const float4*)&xs[r + 32][in];
            s0.x = fmaf(x0.x, w4.x, s0.x); s0.y = fmaf(x0.y, w4.y, s0.y);
            s0.z = fmaf(x0.z, w4.z, s0.z); s0.w = fmaf(x0.w, w4.w, s0.w);
            s1.x = fmaf(x1.x, w4.x, s1.x); s1.y = fmaf(x1.y, w4.y, s1.y);
            s1.z = fmaf(x1.z, w4.z, s1.z); s1.w = fmaf(x1.w, w4.w, s1.w);
        }
        const float a0 = bias + ((s0.x + s0.y) + (s0.z + s0.w));
        const float a1 = bias + ((s1.x + s1.y) + (s1.z + s1.w));
        q[(size_t)(b * KQN + r) * DM + oo] = a0;
        q[(size_t)(b * KQN + r + 32) * DM + oo] = a1;
    }
}

// ---------------------------------------------------------------------------
// K5 (rewritten): kv projection as bf16 MFMA GEMM.
// C[163840,400] = X[163840,200] · W[400,200]^T + bias, stored bf16 to Kp|Vp.
// Tile: BM=64 x BN=80, K=200 fully resident (padded 232). 4 waves, each wave
// owns 16 rows x 80 cols = 5 x mfma_f32_16x16x32_bf16 accumulators.
// LDS: Xs 29.7K + Ws 37.1K + bias = 67K -> 2 blocks/CU.
// ---------------------------------------------------------------------------
__global__ __launch_bounds__(256) void k_kvproj(
    const float* __restrict__ bands, const unsigned short* __restrict__ Wb,
    const float* __restrict__ ipb, __hip_bfloat16* __restrict__ Kp,
    __hip_bfloat16* __restrict__ Vp)
{
    __shared__ __align__(16) unsigned short Xs[64][KPAD];
    __shared__ __align__(16) unsigned short Ws[80][KPAD];
    __shared__ float Bbias[80];
    const int t  = threadIdx.x;
    const int M0 = blockIdx.x * 64;     // global kv row base
    const int n0 = blockIdx.y * 80;     // output col base (0..400)

    // stage W tile (already bf16+padded): 80*232*2B = 2320 x 16B, contiguous
    {
        const float4* wsrc = (const float4*)(Wb + (size_t)n0 * KPAD);
        float4* wdst = (float4*)&Ws[0][0];
        for (int i = t; i < 2320; i += 256) wdst[i] = wsrc[i];
    }
    if (t < 80) Bbias[t] = ipb[DM + n0 + t];
    // stage X tile: 64 rows x 50 float4, convert fp32 -> bf16
    for (int i = t; i < 64 * 50; i += 256) {
        const int r = i / 50, g = i - r * 50;
        const int gg = M0 + r;
        const int bb = gg / TKV, tk = gg - bb * TKV;
        const int band = tk >> 6, kk = tk & 63;
        const float4 x4 = *(const float4*)(bands
            + ((size_t)((band * BATCH + bb) * KQN + kk)) * DM + g * 4);
        ushort4 u;
        u.x = f2bf(x4.x); u.y = f2bf(x4.y); u.z = f2bf(x4.z); u.w = f2bf(x4.w);
        *(ushort4*)&Xs[r][g * 4] = u;
    }
    // zero-pad cols [200,232)
    for (int i = t; i < 64 * 8; i += 256) {
        const int r = i >> 3, g = i & 7;
        ushort4 z; z.x = 0; z.y = 0; z.z = 0; z.w = 0;
        *(ushort4*)&Xs[r][DM + g * 4] = z;
    }
    __syncthreads();

    const int w = t >> 6, lane = t & 63;
    const int lm = lane & 15, quad = lane >> 4;
    const int m0 = w * 16;
    f32x4 acc[5];
#pragma unroll
    for (int nt = 0; nt < 5; ++nt) acc[nt] = (f32x4){0.f, 0.f, 0.f, 0.f};

#pragma unroll
    for (int ks = 0; ks < 7; ++ks) {                 // 7*32 = 224 >= 200
        const int ka = ks * 32 + quad * 8;
        const bf16x8 a = *(const bf16x8*)&Xs[m0 + lm][ka];
#pragma unroll
        for (int nt = 0; nt < 5; ++nt) {
            const bf16x8 bb8 = *(const bf16x8*)&Ws[nt * 16 + lm][ka];
            acc[nt] = __builtin_amdgcn_mfma_f32_16x16x32_bf16(a, bb8, acc[nt], 0, 0, 0);
        }
    }
    // epilogue: C/D layout col=lane&15, row=quad*4+reg
#pragma unroll
    for (int nt = 0; nt < 5; ++nt) {
        const int col = n0 + nt * 16 + lm;
        const float bias = Bbias[nt * 16 + lm];
#pragma unroll
        for (int reg = 0; reg < 4; ++reg) {
            const int grow = M0 + m0 + quad * 4 + reg;
            const float v = acc[nt][reg] + bias;
            if (col < DM) Kp[(size_t)grow * DM + col] = __float2bfloat16(v);
            else          Vp[(size_t)grow * DM + (col - DM)] = __float2bfloat16(v);
        }
    }
}

// ---------------------------------------------------------------------------
// K6: attention per (b, head). Full 320-key scores in LDS (fp32), softmax, PV.
// ---------------------------------------------------------------------------
__global__ __launch_bounds__(256) void k_attn(
    const float* __restrict__ qbuf, const __hip_bfloat16* __restrict__ Kp,
    const __hip_bfloat16* __restrict__ Vp, float* __restrict__ obuf)
{
    __shared__ float Ks[TKV][52];     // K tile, later reused for V
    __shared__ float sc[KQN][324];    // scores -> probabilities
    __shared__ float m4[KQN][4];
    __shared__ float l4[KQN][4];
    const int b = blockIdx.x, hh = blockIdx.y;
    const int t = threadIdx.x;
    const int qq = t & 63, g = t >> 6;     // g is wave-uniform -> no divergence

    for (int idx = t; idx < TKV * HD; idx += 256) {
        const int key = idx / HD, e = idx - key * HD;
        Ks[key][e] = __bfloat162float(Kp[(size_t)(b * TKV + key) * DM + hh * HD + e]);
    }
    float qreg[HD];
    {
        const float* qp = qbuf + (size_t)(b * KQN + qq) * DM + hh * HD;
#pragma unroll
        for (int e = 0; e < HD; ++e) qreg[e] = qp[e];
    }
    __syncthreads();

    const float scale = 0.14142135623730951f;  // 1/sqrt(50)
    float mloc = -1e30f;
    for (int key = g; key < TKV; key += 4) {
        float4 s4 = {0, 0, 0, 0};
#pragma unroll
        for (int e4 = 0; e4 < 48; e4 += 4) {
            const float4 k4 = *(const float4*)&Ks[key][e4];
            s4.x = fmaf(qreg[e4 + 0], k4.x, s4.x);
            s4.y = fmaf(qreg[e4 + 1], k4.y, s4.y);
            s4.z = fmaf(qreg[e4 + 2], k4.z, s4.z);
            s4.w = fmaf(qreg[e4 + 3], k4.w, s4.w);
        }
        float s = (s4.x + s4.y) + (s4.z + s4.w);
        s = fmaf(qreg[48], Ks[key][48], s);
        s = fmaf(qreg[49], Ks[key][49], s);
        s *= scale;
        sc[qq][key] = s;
        mloc = fmaxf(mloc, s);
    }
    m4[qq][g] = mloc;
    __syncthreads();                       // scores done; Ks now dead
    const float m = fmaxf(fmaxf(m4[qq][0], m4[qq][1]), fmaxf(m4[qq][2], m4[qq][3]));
    float lloc = 0.f;
    for (int key = g; key < TKV; key += 4) {
        const float p = __expf(sc[qq][key] - m);
        sc[qq][key] = p;
        lloc += p;
    }
    l4[qq][g] = lloc;
    for (int idx = t; idx < TKV * HD; idx += 256) {   // overlap V load with softmax
        const int key = idx / HD, e = idx - key * HD;
        Ks[key][e] = __bfloat162float(Vp[(size_t)(b * TKV + key) * DM + hh * HD + e]);
    }
    __syncthreads();

    const float l = (l4[qq][0] + l4[qq][1]) + (l4[qq][2] + l4[qq][3]);
    const float inv = 1.f / l;
    float acc[13];
#pragma unroll
    for (int i = 0; i < 13; ++i) acc[i] = 0.f;
    for (int key = 0; key < TKV; ++key) {
        const float p = sc[qq][key];
#pragma unroll
        for (int i = 0; i < 13; ++i) {
            const int e = g + (i << 2);
            if (e < HD) acc[i] = fmaf(p, Ks[key][e], acc[i]);
        }
    }
    float* op = obuf + (size_t)(b * KQN + qq) * DM + hh * HD;
#pragma unroll
    for (int i = 0; i < 13; ++i) {
        const int e = g + (i << 2);
        if (e < HD) op[e] = acc[i] * inv;
    }
}

// ---------------------------------------------------------------------------
// K7: out = o @ out_w^T + out_b
// ---------------------------------------------------------------------------
__global__ __launch_bounds__(256) void k_outproj(
    const float* __restrict__ obuf, const float* __restrict__ outw,
    const float* __restrict__ outb, float* __restrict__ out)
{
    __shared__ float xs[64][204];
    const int b = blockIdx.x;
    const int t = threadIdx.x;
    for (int idx = t; idx < KQN * DM; idx += 256) {
        const int r = idx / DM, col = idx - r * DM;
        xs[r][col] = obuf[(size_t)(b * KQN + r) * DM + col];
    }
    __syncthreads();
    const int r = t & 31, c = t >> 5;
    for (int oo = c; oo < DM; oo += 8) {
        const float* wrow = outw + (size_t)oo * DM;
        const float bias = outb[oo];
        float4 s0 = {0, 0, 0, 0}, s1 = {0, 0, 0, 0};
        for (int in = 0; in < DM; in += 4) {
            const float4 w4 = *(const float4*)(wrow + in);
            const float4 x0 = *(const float4*)&xs[r][in];
            const float4 x1 = *(const float4*)&xs[r + 32][in];
            s0.x = fmaf(x0.x, w4.x, s0.x); s0.y = fmaf(x0.y, w4.y, s0.y);
            s0.z = fmaf(x0.z, w4.z, s0.z); s0.w = fmaf(x0.w, w4.w, s0.w);
            s1.x = fmaf(x1.x, w4.x, s1.x); s1.y = fmaf(x1.y, w4.y, s1.y);
            s1.z = fmaf(x1.z, w4.z, s1.z); s1.w = fmaf(x1.w, w4.w, s1.w);
        }
        const float a0 = bias + ((s0.x + s0.y) + (s0.z + s0.w));
        const float a1 = bias + ((s1.x + s1.y) + (s1.z + s1.w));
        out[(size_t)(b * KQN + r) * DM + oo] = a0;
        out[(size_t)(b * KQN + r + 32) * DM + oo] = a1;
    }
}

// ---------------------------------------------------------------------------
// Workspace layout (bytes):
//   part  fp32 [8][512][512]      @ 0          ( 8,388,608)   } Wb bf16 [400][232]
//   h     fp32 [512][512]         @ 8388608    ( 1,048,576)   } overlaps part@0
//   sel   int  [512]              @ 9437184    (     2,048)   } (wprep runs after
//   q     fp32 [512][64][200]     @ 9439232    (26,214,400)   }  reduce_relu)
//   Kp    bf16 [512][320][200]    @ 35653632   (65,536,000)
//   Vp    bf16 [512][320][200]    @ 101189632  (65,536,000)
//   obuf  fp32 [512][64][200]     @ 166725632  (26,214,400)
//   total 192,940,032 bytes
// ---------------------------------------------------------------------------
extern "C" void kernel_launch(void* const* d_in, const int* in_sizes, int n_in,
                              void* d_out, int out_size, void* d_ws, size_t ws_size,
                              hipStream_t stream)
{
    const float* bands = (const float*)d_in[0];
    const float* w1    = (const float*)d_in[1];
    const float* b1    = (const float*)d_in[2];
    const float* w2    = (const float*)d_in[3];
    const float* b2    = (const float*)d_in[4];
    const float* ipw   = (const float*)d_in[5];
    const float* ipb   = (const float*)d_in[6];
    const float* outw  = (const float*)d_in[7];
    const float* outb  = (const float*)d_in[8];
    float* out = (float*)d_out;

    if (ws_size < (size_t)192940032) return;  // layout needs 193 MB scratch

    char* ws = (char*)d_ws;
    float* part = (float*)(ws + 0);
    unsigned short* Wb = (unsigned short*)(ws + 0);  // overlaps part (dead by then)
    float* h    = (float*)(ws + 8388608);
    int*   sel  = (int*)  (ws + 9437184);
    float* q    = (float*)(ws + 9439232);
    __hip_bfloat16* Kp = (__hip_bfloat16*)(ws + 35653632);
    __hip_bfloat16* Vp = (__hip_bfloat16*)(ws + 101189632);
    float* obuf = (float*)(ws + 166725632);

    k_router_gemm<<<dim3(8, 8, KSPLIT), 256, 0, stream>>>(bands, w1, part);
    k_reduce_relu<<<(BATCH * HIDW) / 256, 256, 0, stream>>>(part, b1, h);
    k_wprep<<<400, 256, 0, stream>>>(ipw, Wb);      // part is dead now
    k_argmax<<<BATCH, 256, 0, stream>>>(h, w2, b2, sel);
    k_qproj<<<BATCH, 256, 0, stream>>>(bands, sel, ipw, ipb, q);
    k_kvproj<<<dim3(2560, 5), 256, 0, stream>>>(bands, Wb, ipb, Kp, Vp);
    k_attn<<<dim3(BATCH, NHEAD), 256, 0, stream>>>(q, Kp, Vp, obuf);
    k_outproj<<<BATCH, 256, 0, stream>>>(obuf, outw, outb, out);
}

// Round 3
// 1804.030 us; speedup vs baseline: 2.2788x; 1.4267x over previous
//
#include <hip/hip_runtime.h>
#include <hip/hip_bf16.h>

// Problem constants
#define NBANDS 5
#define BATCH  512
#define KQN    64     // queries per sample
#define DM     200    // model dim
#define NHEAD  4
#define HD     50     // head dim
#define HIDW   512    // router hidden
#define TKV    320    // NBANDS*KQN keys
#define FIN    64000  // NBANDS*KQN*DM
#define KSPLIT 8
#define KCH    8000   // FIN/KSPLIT
#define KPAD   232    // padded K for bf16 LDS tiles (200 data + zeros)

typedef __bf16  bf16x8 __attribute__((ext_vector_type(8)));
typedef float   f32x4  __attribute__((ext_vector_type(4)));

static __device__ inline unsigned short f2bf(float f) {
    __hip_bfloat16 h = __float2bfloat16(f);
    return *reinterpret_cast<unsigned short*>(&h);
}

// ---------------------------------------------------------------------------
// K1: router GEMM partials: part[z][b][j] = sum_{ki in chunk z} flat[b,ki]*w1[j,ki]
// fp32 (precision-critical: argmax flips if done in bf16). 64x64 tile, 4x4/thread.
// ---------------------------------------------------------------------------
__global__ __launch_bounds__(256) void k_router_gemm(
    const float* __restrict__ bands, const float* __restrict__ w1,
    float* __restrict__ part)
{
    __shared__ float As[16][68];
    __shared__ float Bs[16][68];
    const int j0 = blockIdx.x * 64;
    const int b0 = blockIdx.y * 64;
    const int z  = blockIdx.z;
    const int t  = threadIdx.x;
    const int tx = t & 15, ty = t >> 4;
    const int lm = t >> 2;          // 0..63 (row within tile for loading)
    const int lk = (t & 3) << 2;    // 0,4,8,12
    float acc[4][4] = {};
    const int kbase = z * KCH;
    for (int ks = 0; ks < KCH; ks += 16) {
        const int ki   = kbase + ks + lk;
        const int band = ki / 12800;   // aligned 4-groups never cross a band
        const float4 a4 = *(const float4*)(bands + (size_t)(b0 + lm) * 12800 + ki
                                           + (size_t)band * 6540800);
        const float4 b4 = *(const float4*)(w1 + (size_t)(j0 + lm) * FIN + ki);
        __syncthreads();   // previous compute done before LDS overwrite
        As[lk + 0][lm] = a4.x; As[lk + 1][lm] = a4.y;
        As[lk + 2][lm] = a4.z; As[lk + 3][lm] = a4.w;
        Bs[lk + 0][lm] = b4.x; Bs[lk + 1][lm] = b4.y;
        Bs[lk + 2][lm] = b4.z; Bs[lk + 3][lm] = b4.w;
        __syncthreads();
#pragma unroll
        for (int kk = 0; kk < 16; ++kk) {
            const float4 av = *(const float4*)&As[kk][ty << 2];
            const float4 bv = *(const float4*)&Bs[kk][tx << 2];
            const float a_[4] = {av.x, av.y, av.z, av.w};
            const float b_[4] = {bv.x, bv.y, bv.z, bv.w};
#pragma unroll
            for (int i = 0; i < 4; ++i)
#pragma unroll
                for (int j = 0; j < 4; ++j)
                    acc[i][j] = fmaf(a_[i], b_[j], acc[i][j]);
        }
    }
    float* po = part + (size_t)z * (BATCH * HIDW);
#pragma unroll
    for (int i = 0; i < 4; ++i) {
        const int bb = b0 + (ty << 2) + i;
#pragma unroll
        for (int j = 0; j < 4; ++j)
            po[bb * HIDW + j0 + (tx << 2) + j] = acc[i][j];
    }
}

// ---------------------------------------------------------------------------
// K2: h = relu(sum_z part + b1)
// ---------------------------------------------------------------------------
__global__ __launch_bounds__(256) void k_reduce_relu(
    const float* __restrict__ part, const float* __restrict__ b1,
    float* __restrict__ h)
{
    const int tid = blockIdx.x * 256 + threadIdx.x;  // < BATCH*HIDW
    float s = b1[tid & (HIDW - 1)];
#pragma unroll
    for (int z = 0; z < KSPLIT; ++z) s += part[z * (BATCH * HIDW) + tid];
    h[tid] = fmaxf(s, 0.f);
}

// ---------------------------------------------------------------------------
// K2b: pre-convert in_proj rows 200..599 (wk|wv) to bf16, K padded to 232.
// ---------------------------------------------------------------------------
__global__ __launch_bounds__(256) void k_wprep(
    const float* __restrict__ ipw, unsigned short* __restrict__ Wb)
{
    const int j = blockIdx.x;        // 0..399
    const int c = threadIdx.x;       // 0..255 (232 active)
    if (c < KPAD) {
        const float v = (c < DM) ? ipw[(size_t)(DM + j) * DM + c] : 0.f;
        Wb[(size_t)j * KPAD + c] = f2bf(v);
    }
}

// ---------------------------------------------------------------------------
// K3: logits = h @ w2^T + b2 ; sel = argmax (softmax is monotonic -> skip it)
// ---------------------------------------------------------------------------
__global__ __launch_bounds__(256) void k_argmax(
    const float* __restrict__ h, const float* __restrict__ w2,
    const float* __restrict__ b2, int* __restrict__ sel)
{
    __shared__ float red[NBANDS][256];
    const int b = blockIdx.x, t = threadIdx.x;
    float acc[NBANDS] = {0.f, 0.f, 0.f, 0.f, 0.f};
    for (int j = t; j < HIDW; j += 256) {
        const float hv = h[b * HIDW + j];
#pragma unroll
        for (int n = 0; n < NBANDS; ++n)
            acc[n] = fmaf(hv, w2[n * HIDW + j], acc[n]);
    }
#pragma unroll
    for (int n = 0; n < NBANDS; ++n) red[n][t] = acc[n];
    __syncthreads();
    for (int s = 128; s > 0; s >>= 1) {
        if (t < s) {
#pragma unroll
            for (int n = 0; n < NBANDS; ++n) red[n][t] += red[n][t + s];
        }
        __syncthreads();
    }
    if (t == 0) {
        int best = 0;
        float bv = red[0][0] + b2[0];
        for (int n = 1; n < NBANDS; ++n) {
            const float v = red[n][0] + b2[n];
            if (v > bv) { bv = v; best = n; }
        }
        sel[b] = best;
    }
}

// ---------------------------------------------------------------------------
// K4: q projection for the selected band (fp32 — feeds scores, keep precise)
// ---------------------------------------------------------------------------
__global__ __launch_bounds__(256) void k_qproj(
    const float* __restrict__ bands, const int* __restrict__ sel,
    const float* __restrict__ ipw, const float* __restrict__ ipb,
    float* __restrict__ q)
{
    __shared__ float xs[64][204];
    const int b = blockIdx.x;
    const int t = threadIdx.x;
    const int band = sel[b];
    for (int idx = t; idx < KQN * DM; idx += 256) {
        const int r = idx / DM, col = idx - r * DM;
        xs[r][col] = bands[(size_t)((band * BATCH + b) * KQN + r) * DM + col];
    }
    __syncthreads();
    const int r = t & 31, c = t >> 5;
    for (int oo = c; oo < DM; oo += 8) {
        const float* wrow = ipw + (size_t)oo * DM;   // wq rows 0..199
        const float bias = ipb[oo];
        float4 s0 = {0, 0, 0, 0}, s1 = {0, 0, 0, 0};
        for (int in = 0; in < DM; in += 4) {
            const float4 w4 = *(const float4*)(wrow + in);
            const float4 x0 = *(const float4*)&xs[r][in];
            const float4 x1 = *(const float4*)&xs[r + 32][in];
            s0.x = fmaf(x0.x, w4.x, s0.x); s0.y = fmaf(x0.y, w4.y, s0.y);
            s0.z = fmaf(x0.z, w4.z, s0.z); s0.w = fmaf(x0.w, w4.w, s0.w);
            s1.x = fmaf(x1.x, w4.x, s1.x); s1.y = fmaf(x1.y, w4.y, s1.y);
            s1.z = fmaf(x1.z, w4.z, s1.z); s1.w = fmaf(x1.w, w4.w, s1.w);
        }
        const float a0 = bias + ((s0.x + s0.y) + (s0.z + s0.w));
        const float a1 = bias + ((s1.x + s1.y) + (s1.z + s1.w));
        q[(size_t)(b * KQN + r) * DM + oo] = a0;
        q[(size_t)(b * KQN + r + 32) * DM + oo] = a1;
    }
}

// ---------------------------------------------------------------------------
// K5: kv projection as bf16 MFMA GEMM (unchanged from R2).
// ---------------------------------------------------------------------------
__global__ __launch_bounds__(256) void k_kvproj(
    const float* __restrict__ bands, const unsigned short* __restrict__ Wb,
    const float* __restrict__ ipb, __hip_bfloat16* __restrict__ Kp,
    __hip_bfloat16* __restrict__ Vp)
{
    __shared__ __align__(16) unsigned short Xs[64][KPAD];
    __shared__ __align__(16) unsigned short Ws[80][KPAD];
    __shared__ float Bbias[80];
    const int t  = threadIdx.x;
    const int M0 = blockIdx.x * 64;     // global kv row base
    const int n0 = blockIdx.y * 80;     // output col base (0..400)

    {
        const float4* wsrc = (const float4*)(Wb + (size_t)n0 * KPAD);
        float4* wdst = (float4*)&Ws[0][0];
        for (int i = t; i < 2320; i += 256) wdst[i] = wsrc[i];
    }
    if (t < 80) Bbias[t] = ipb[DM + n0 + t];
    for (int i = t; i < 64 * 50; i += 256) {
        const int r = i / 50, g = i - r * 50;
        const int gg = M0 + r;
        const int bb = gg / TKV, tk = gg - bb * TKV;
        const int band = tk >> 6, kk = tk & 63;
        const float4 x4 = *(const float4*)(bands
            + ((size_t)((band * BATCH + bb) * KQN + kk)) * DM + g * 4);
        ushort4 u;
        u.x = f2bf(x4.x); u.y = f2bf(x4.y); u.z = f2bf(x4.z); u.w = f2bf(x4.w);
        *(ushort4*)&Xs[r][g * 4] = u;
    }
    for (int i = t; i < 64 * 8; i += 256) {
        const int r = i >> 3, g = i & 7;
        ushort4 z; z.x = 0; z.y = 0; z.z = 0; z.w = 0;
        *(ushort4*)&Xs[r][DM + g * 4] = z;
    }
    __syncthreads();

    const int w = t >> 6, lane = t & 63;
    const int lm = lane & 15, quad = lane >> 4;
    const int m0 = w * 16;
    f32x4 acc[5];
#pragma unroll
    for (int nt = 0; nt < 5; ++nt) acc[nt] = (f32x4){0.f, 0.f, 0.f, 0.f};

#pragma unroll
    for (int ks = 0; ks < 7; ++ks) {                 // 7*32 = 224 >= 200
        const int ka = ks * 32 + quad * 8;
        const bf16x8 a = *(const bf16x8*)&Xs[m0 + lm][ka];
#pragma unroll
        for (int nt = 0; nt < 5; ++nt) {
            const bf16x8 bb8 = *(const bf16x8*)&Ws[nt * 16 + lm][ka];
            acc[nt] = __builtin_amdgcn_mfma_f32_16x16x32_bf16(a, bb8, acc[nt], 0, 0, 0);
        }
    }
#pragma unroll
    for (int nt = 0; nt < 5; ++nt) {
        const int col = n0 + nt * 16 + lm;
        const float bias = Bbias[nt * 16 + lm];
#pragma unroll
        for (int reg = 0; reg < 4; ++reg) {
            const int grow = M0 + m0 + quad * 4 + reg;
            const float v = acc[nt][reg] + bias;
            if (col < DM) Kp[(size_t)grow * DM + col] = __float2bfloat16(v);
            else          Vp[(size_t)grow * DM + (col - DM)] = __float2bfloat16(v);
        }
    }
}

// ---------------------------------------------------------------------------
// K6 (rewritten): MFMA attention per (b, head).
// Phase 1: S = Q·K^T via mfma_16x16x32_bf16, k-dim 50 padded to 64.
//   Wave w owns queries [16w,16w+16): 20 n-tiles (320 keys), acc in 80 VGPRs.
// Softmax: C-layout row = quad*4+reg lives in fixed lanes -> register-only
//   row max/sum via 4 __shfl_xor (within quad's 16 lanes). inv kept in regs.
// P -> LDS bf16 (A-operand layout), V pre-transposed in LDS -> Phase 2 PV.
// All LDS row strides chosen so lane stride maps to bank step 4 (2-way, free).
// LDS: Qs 9216 + KP 46080 + Vt 41984 + Ps 41984 = 139264 B (1 block/CU).
// ---------------------------------------------------------------------------
__global__ __launch_bounds__(256) void k_attn(
    const float* __restrict__ qbuf, const __hip_bfloat16* __restrict__ Kp,
    const __hip_bfloat16* __restrict__ Vp, float* __restrict__ obuf)
{
    __shared__ __align__(16) unsigned short Qs[64][72];    // [query][k 0..63]
    __shared__ __align__(16) unsigned short KP[320][72];   // [key][k 0..63]
    __shared__ __align__(16) unsigned short Vt[64][328];   // [e][key]
    __shared__ __align__(16) unsigned short Ps[64][328];   // [query][key]
    const int b = blockIdx.x, hh = blockIdx.y;
    const int t = threadIdx.x;

    // ---- stage Q (fp32 -> bf16), zero k-pad [50,64) ----
    for (int idx = t; idx < 64 * 64; idx += 256) {
        const int r = idx >> 6, e = idx & 63;
        const float v = (e < HD) ? qbuf[(size_t)(b * KQN + r) * DM + hh * HD + e] : 0.f;
        Qs[r][e] = f2bf(v);
    }
    // ---- stage K rows (bf16, ushort2 granules) ----
    const unsigned short* kbase = (const unsigned short*)Kp + (size_t)b * TKV * DM + hh * HD;
    for (int idx = t; idx < 320 * 25; idx += 256) {
        const int key = idx / 25, g = idx - key * 25;
        *(unsigned int*)&KP[key][g * 2] =
            *(const unsigned int*)(kbase + (size_t)key * DM + g * 2);
    }
    for (int idx = t; idx < 320 * 7; idx += 256) {   // zero k-pad [50,64)
        const int key = idx / 7, g = idx - key * 7;
        *(unsigned int*)&KP[key][50 + g * 2] = 0;
    }
    // ---- stage V transposed: Vt[e][key] (rows e>=50 garbage -> discarded cols) ----
    const unsigned short* vbase = (const unsigned short*)Vp + (size_t)b * TKV * DM + hh * HD;
    for (int idx = t; idx < 320 * 25; idx += 256) {
        const int key = idx / 25, g = idx - key * 25;
        const unsigned int v = *(const unsigned int*)(vbase + (size_t)key * DM + g * 2);
        Vt[g * 2][key]     = (unsigned short)(v & 0xffffu);
        Vt[g * 2 + 1][key] = (unsigned short)(v >> 16);
    }
    __syncthreads();

    const int w = t >> 6, lane = t & 63;
    const int lm = lane & 15, quad = lane >> 4;
    const int m0 = w * 16;

    // ---- Phase 1: S = Q·K^T ----
    f32x4 s[20];
#pragma unroll
    for (int nt = 0; nt < 20; ++nt) s[nt] = (f32x4){0.f, 0.f, 0.f, 0.f};
#pragma unroll
    for (int ks = 0; ks < 2; ++ks) {
        const int ka = ks * 32 + quad * 8;
        const bf16x8 a = *(const bf16x8*)&Qs[m0 + lm][ka];
#pragma unroll
        for (int nt = 0; nt < 20; ++nt) {
            const bf16x8 bb8 = *(const bf16x8*)&KP[nt * 16 + lm][ka];
            s[nt] = __builtin_amdgcn_mfma_f32_16x16x32_bf16(a, bb8, s[nt], 0, 0, 0);
        }
    }

    // ---- softmax in registers; row = m0 + quad*4 + reg, cols nt*16+lm ----
    const float scale = 0.14142135623730951f;  // 1/sqrt(50)
    float inv[4];
#pragma unroll
    for (int reg = 0; reg < 4; ++reg) {
        float mx = -1e30f;
#pragma unroll
        for (int nt = 0; nt < 20; ++nt) {
            const float sv = s[nt][reg] * scale;
            s[nt][reg] = sv;
            mx = fmaxf(mx, sv);
        }
#pragma unroll
        for (int off = 1; off < 16; off <<= 1)
            mx = fmaxf(mx, __shfl_xor(mx, off, 64));
        float lsum = 0.f;
#pragma unroll
        for (int nt = 0; nt < 20; ++nt) {
            const float p = __expf(s[nt][reg] - mx);
            s[nt][reg] = p;
            lsum += p;
        }
#pragma unroll
        for (int off = 1; off < 16; off <<= 1)
            lsum += __shfl_xor(lsum, off, 64);
        inv[reg] = 1.f / lsum;
    }
    // ---- write P (bf16) in A-operand-friendly layout ----
#pragma unroll
    for (int reg = 0; reg < 4; ++reg) {
        const int row = m0 + quad * 4 + reg;
#pragma unroll
        for (int nt = 0; nt < 20; ++nt)
            Ps[row][nt * 16 + lm] = f2bf(s[nt][reg]);
    }
    __syncthreads();

    // ---- Phase 2: O = P·V ----
    f32x4 o[4];
#pragma unroll
    for (int nt = 0; nt < 4; ++nt) o[nt] = (f32x4){0.f, 0.f, 0.f, 0.f};
#pragma unroll
    for (int ks = 0; ks < 10; ++ks) {
        const int ka = ks * 32 + quad * 8;
        const bf16x8 a = *(const bf16x8*)&Ps[m0 + lm][ka];
#pragma unroll
        for (int nt = 0; nt < 4; ++nt) {
            const bf16x8 bb8 = *(const bf16x8*)&Vt[nt * 16 + lm][ka];
            o[nt] = __builtin_amdgcn_mfma_f32_16x16x32_bf16(a, bb8, o[nt], 0, 0, 0);
        }
    }
    float* op = obuf + (size_t)(b * KQN) * DM + hh * HD;
#pragma unroll
    for (int nt = 0; nt < 4; ++nt) {
        const int e = nt * 16 + lm;
        if (e < HD) {
#pragma unroll
            for (int reg = 0; reg < 4; ++reg) {
                const int row = m0 + quad * 4 + reg;
                op[(size_t)row * DM + e] = o[nt][reg] * inv[reg];
            }
        }
    }
}

// ---------------------------------------------------------------------------
// K7: out = o @ out_w^T + out_b
// ---------------------------------------------------------------------------
__global__ __launch_bounds__(256) void k_outproj(
    const float* __restrict__ obuf, const float* __restrict__ outw,
    const float* __restrict__ outb, float* __restrict__ out)
{
    __shared__ float xs[64][204];
    const int b = blockIdx.x;
    const int t = threadIdx.x;
    for (int idx = t; idx < KQN * DM; idx += 256) {
        const int r = idx / DM, col = idx - r * DM;
        xs[r][col] = obuf[(size_t)(b * KQN + r) * DM + col];
    }
    __syncthreads();
    const int r = t & 31, c = t >> 5;
    for (int oo = c; oo < DM; oo += 8) {
        const float* wrow = outw + (size_t)oo * DM;
        const float bias = outb[oo];
        float4 s0 = {0, 0, 0, 0}, s1 = {0, 0, 0, 0};
        for (int in = 0; in < DM; in += 4) {
            const float4 w4 = *(const float4*)(wrow + in);
            const float4 x0 = *(const float4*)&xs[r][in];
            const float4 x1 = *(const float4*)&xs[r + 32][in];
            s0.x = fmaf(x0.x, w4.x, s0.x); s0.y = fmaf(x0.y, w4.y, s0.y);
            s0.z = fmaf(x0.z, w4.z, s0.z); s0.w = fmaf(x0.w, w4.w, s0.w);
            s1.x = fmaf(x1.x, w4.x, s1.x); s1.y = fmaf(x1.y, w4.y, s1.y);
            s1.z = fmaf(x1.z, w4.z, s1.z); s1.w = fmaf(x1.w, w4.w, s1.w);
        }
        const float a0 = bias + ((s0.x + s0.y) + (s0.z + s0.w));
        const float a1 = bias + ((s1.x + s1.y) + (s1.z + s1.w));
        out[(size_t)(b * KQN + r) * DM + oo] = a0;
        out[(size_t)(b * KQN + r + 32) * DM + oo] = a1;
    }
}

// ---------------------------------------------------------------------------
// Workspace layout: unchanged (193 MB)
// ---------------------------------------------------------------------------
extern "C" void kernel_launch(void* const* d_in, const int* in_sizes, int n_in,
                              void* d_out, int out_size, void* d_ws, size_t ws_size,
                              hipStream_t stream)
{
    const float* bands = (const float*)d_in[0];
    const float* w1    = (const float*)d_in[1];
    const float* b1    = (const float*)d_in[2];
    const float* w2    = (const float*)d_in[3];
    const float* b2    = (const float*)d_in[4];
    const float* ipw   = (const float*)d_in[5];
    const float* ipb   = (const float*)d_in[6];
    const float* outw  = (const float*)d_in[7];
    const float* outb  = (const float*)d_in[8];
    float* out = (float*)d_out;

    if (ws_size < (size_t)192940032) return;

    char* ws = (char*)d_ws;
    float* part = (float*)(ws + 0);
    unsigned short* Wb = (unsigned short*)(ws + 0);  // overlaps part (dead by then)
    float* h    = (float*)(ws + 8388608);
    int*   sel  = (int*)  (ws + 9437184);
    float* q    = (float*)(ws + 9439232);
    __hip_bfloat16* Kp = (__hip_bfloat16*)(ws + 35653632);
    __hip_bfloat16* Vp = (__hip_bfloat16*)(ws + 101189632);
    float* obuf = (float*)(ws + 166725632);

    k_router_gemm<<<dim3(8, 8, KSPLIT), 256, 0, stream>>>(bands, w1, part);
    k_reduce_relu<<<(BATCH * HIDW) / 256, 256, 0, stream>>>(part, b1, h);
    k_wprep<<<400, 256, 0, stream>>>(ipw, Wb);      // part is dead now
    k_argmax<<<BATCH, 256, 0, stream>>>(h, w2, b2, sel);
    k_qproj<<<BATCH, 256, 0, stream>>>(bands, sel, ipw, ipb, q);
    k_kvproj<<<dim3(2560, 5), 256, 0, stream>>>(bands, Wb, ipb, Kp, Vp);
    k_attn<<<dim3(BATCH, NHEAD), 256, 0, stream>>>(q, Kp, Vp, obuf);
    k_outproj<<<BATCH, 256, 0, stream>>>(obuf, outw, outb, out);
}

// Round 4
// 1669.147 us; speedup vs baseline: 2.4630x; 1.0808x over previous
//
#include <hip/hip_runtime.h>
#include <hip/hip_bf16.h>

// Problem constants
#define NBANDS 5
#define BATCH  512
#define KQN    64     // queries per sample
#define DM     200    // model dim
#define NHEAD  4
#define HD     50     // head dim
#define HIDW   512    // router hidden
#define TKV    320    // NBANDS*KQN keys
#define FIN    64000  // NBANDS*KQN*DM
#define KSPLIT 8
#define KCH    8000   // FIN/KSPLIT
#define KPAD   232    // padded K for bf16 LDS tiles (200 data + zeros)

typedef __bf16  bf16x8 __attribute__((ext_vector_type(8)));
typedef float   f32x4  __attribute__((ext_vector_type(4)));

static __device__ inline unsigned short f2bf(float f) {
    __hip_bfloat16 h = __float2bfloat16(f);
    return *reinterpret_cast<unsigned short*>(&h);
}
static __device__ inline float bf2f(unsigned short u) {
    union { unsigned int i; float f; } x;
    x.i = ((unsigned int)u) << 16;
    return x.f;
}

// ---------------------------------------------------------------------------
// K0: pre-convert w1 (fp32) into Markidis hi/lo bf16 planes.
// wH[i] = bf16(w1[i]); wL[i] = bf16(w1[i] - float(wH[i])). Pure-BW pass.
// ---------------------------------------------------------------------------
__global__ __launch_bounds__(256) void k_conv_w1(
    const float* __restrict__ w1, unsigned short* __restrict__ wH,
    unsigned short* __restrict__ wL)
{
    const size_t i = ((size_t)blockIdx.x * 256 + threadIdx.x) * 4;
    const float4 f = *(const float4*)(w1 + i);
    ushort4 h, l;
    h.x = f2bf(f.x); l.x = f2bf(f.x - bf2f(h.x));
    h.y = f2bf(f.y); l.y = f2bf(f.y - bf2f(h.y));
    h.z = f2bf(f.z); l.z = f2bf(f.z - bf2f(h.z));
    h.w = f2bf(f.w); l.w = f2bf(f.w - bf2f(h.w));
    *(ushort4*)(wH + i) = h;
    *(ushort4*)(wL + i) = l;
}

// ---------------------------------------------------------------------------
// K1 (rewritten): router GEMM via 3-product split-bf16 MFMA.
// part[z][b][j] = sum_{ki in chunk z} flat[b,ki] * w1[j,ki]
//   flat[b,ki] = bands[band*6540800 + b*12800 + ki], band = ki/12800
//   (64-aligned chunks never cross a band: 12800 % 64 == 0)
// acc += Ah*Bh + Ah*Bl + Al*Bh   (fp32 accumulate; residual ~2^-18 per term
//   -> logit error ~1e-5 << min top-2 gap ~3e-3 -> argmax-safe)
// Tile 64x64, BK=64, 4 waves each 16 rows x 64 cols. LDS 36.9 KB -> 4 blk/CU.
// ---------------------------------------------------------------------------
__global__ __launch_bounds__(256) void k_router_mfma(
    const float* __restrict__ bands, const unsigned short* __restrict__ wH,
    const unsigned short* __restrict__ wL, float* __restrict__ part)
{
    __shared__ __align__(16) unsigned short Ah[64][72];
    __shared__ __align__(16) unsigned short Al[64][72];
    __shared__ __align__(16) unsigned short Bh[64][72];
    __shared__ __align__(16) unsigned short Bl[64][72];
    const int j0 = blockIdx.x * 64;
    const int b0 = blockIdx.y * 64;
    const int z  = blockIdx.z;
    const int t  = threadIdx.x;
    const int w  = t >> 6, lane = t & 63;
    const int lm = lane & 15, quad = lane >> 4;
    const int m0 = w * 16;

    // staging index precompute
    const int arow0 = t >> 4,  ac4 = (t & 15) * 4;   // A: 4 rows/pass of 16 float4
    const int brow0 = t >> 3,  bc8 = (t & 7) * 8;    // B: 2 rows/pass of 8 ushort8

    f32x4 acc[4];
#pragma unroll
    for (int nt = 0; nt < 4; ++nt) acc[nt] = (f32x4){0.f, 0.f, 0.f, 0.f};

    const int kbase = z * KCH;
    for (int chunk = 0; chunk < 125; ++chunk) {
        const int kc = kbase + chunk * 64;
        const int band = kc / 12800;
        const float* abase = bands + (size_t)band * 6540800 + kc;
        // ---- load to regs ----
        float4 av[4];
#pragma unroll
        for (int r = 0; r < 4; ++r)
            av[r] = *(const float4*)(abase + (size_t)(b0 + arow0 + r * 16) * 12800 + ac4);
        uint4 bh[2], bl[2];
#pragma unroll
        for (int r = 0; r < 2; ++r) {
            const size_t off = (size_t)(j0 + brow0 + r * 32) * FIN + kc + bc8;
            bh[r] = *(const uint4*)(wH + off);
            bl[r] = *(const uint4*)(wL + off);
        }
        __syncthreads();   // previous chunk's MFMA LDS reads complete
        // ---- convert A to hi/lo, write LDS ----
#pragma unroll
        for (int r = 0; r < 4; ++r) {
            const int row = arow0 + r * 16;
            ushort4 hh, ll;
            hh.x = f2bf(av[r].x); ll.x = f2bf(av[r].x - bf2f(hh.x));
            hh.y = f2bf(av[r].y); ll.y = f2bf(av[r].y - bf2f(hh.y));
            hh.z = f2bf(av[r].z); ll.z = f2bf(av[r].z - bf2f(hh.z));
            hh.w = f2bf(av[r].w); ll.w = f2bf(av[r].w - bf2f(hh.w));
            *(ushort4*)&Ah[row][ac4] = hh;
            *(ushort4*)&Al[row][ac4] = ll;
        }
#pragma unroll
        for (int r = 0; r < 2; ++r) {
            const int row = brow0 + r * 32;
            *(uint4*)&Bh[row][bc8] = bh[r];
            *(uint4*)&Bl[row][bc8] = bl[r];
        }
        __syncthreads();
        // ---- 3-product MFMA ----
#pragma unroll
        for (int ks = 0; ks < 2; ++ks) {
            const int ka = ks * 32 + quad * 8;
            const bf16x8 a_h = *(const bf16x8*)&Ah[m0 + lm][ka];
            const bf16x8 a_l = *(const bf16x8*)&Al[m0 + lm][ka];
#pragma unroll
            for (int nt = 0; nt < 4; ++nt) {
                const bf16x8 b_h = *(const bf16x8*)&Bh[nt * 16 + lm][ka];
                const bf16x8 b_l = *(const bf16x8*)&Bl[nt * 16 + lm][ka];
                acc[nt] = __builtin_amdgcn_mfma_f32_16x16x32_bf16(a_h, b_h, acc[nt], 0, 0, 0);
                acc[nt] = __builtin_amdgcn_mfma_f32_16x16x32_bf16(a_l, b_h, acc[nt], 0, 0, 0);
                acc[nt] = __builtin_amdgcn_mfma_f32_16x16x32_bf16(a_h, b_l, acc[nt], 0, 0, 0);
            }
        }
    }
    // epilogue: row (batch) = b0+m0+quad*4+reg, col (j) = j0+nt*16+lm
    float* po = part + (size_t)z * (BATCH * HIDW);
#pragma unroll
    for (int nt = 0; nt < 4; ++nt) {
        const int jj = j0 + nt * 16 + lm;
#pragma unroll
        for (int reg = 0; reg < 4; ++reg) {
            const int bb = b0 + m0 + quad * 4 + reg;
            po[(size_t)bb * HIDW + jj] = acc[nt][reg];
        }
    }
}

// ---------------------------------------------------------------------------
// K2: h = relu(sum_z part + b1)
// ---------------------------------------------------------------------------
__global__ __launch_bounds__(256) void k_reduce_relu(
    const float* __restrict__ part, const float* __restrict__ b1,
    float* __restrict__ h)
{
    const int tid = blockIdx.x * 256 + threadIdx.x;  // < BATCH*HIDW
    float s = b1[tid & (HIDW - 1)];
#pragma unroll
    for (int z = 0; z < KSPLIT; ++z) s += part[z * (BATCH * HIDW) + tid];
    h[tid] = fmaxf(s, 0.f);
}

// ---------------------------------------------------------------------------
// K2b: pre-convert in_proj rows 200..599 (wk|wv) to bf16, K padded to 232.
// ---------------------------------------------------------------------------
__global__ __launch_bounds__(256) void k_wprep(
    const float* __restrict__ ipw, unsigned short* __restrict__ Wb)
{
    const int j = blockIdx.x;        // 0..399
    const int c = threadIdx.x;       // 0..255 (232 active)
    if (c < KPAD) {
        const float v = (c < DM) ? ipw[(size_t)(DM + j) * DM + c] : 0.f;
        Wb[(size_t)j * KPAD + c] = f2bf(v);
    }
}

// ---------------------------------------------------------------------------
// K3: logits = h @ w2^T + b2 ; sel = argmax (softmax is monotonic -> skip it)
// ---------------------------------------------------------------------------
__global__ __launch_bounds__(256) void k_argmax(
    const float* __restrict__ h, const float* __restrict__ w2,
    const float* __restrict__ b2, int* __restrict__ sel)
{
    __shared__ float red[NBANDS][256];
    const int b = blockIdx.x, t = threadIdx.x;
    float acc[NBANDS] = {0.f, 0.f, 0.f, 0.f, 0.f};
    for (int j = t; j < HIDW; j += 256) {
        const float hv = h[b * HIDW + j];
#pragma unroll
        for (int n = 0; n < NBANDS; ++n)
            acc[n] = fmaf(hv, w2[n * HIDW + j], acc[n]);
    }
#pragma unroll
    for (int n = 0; n < NBANDS; ++n) red[n][t] = acc[n];
    __syncthreads();
    for (int s = 128; s > 0; s >>= 1) {
        if (t < s) {
#pragma unroll
            for (int n = 0; n < NBANDS; ++n) red[n][t] += red[n][t + s];
        }
        __syncthreads();
    }
    if (t == 0) {
        int best = 0;
        float bv = red[0][0] + b2[0];
        for (int n = 1; n < NBANDS; ++n) {
            const float v = red[n][0] + b2[n];
            if (v > bv) { bv = v; best = n; }
        }
        sel[b] = best;
    }
}

// ---------------------------------------------------------------------------
// K4: q projection for the selected band (fp32 — feeds scores, keep precise)
// ---------------------------------------------------------------------------
__global__ __launch_bounds__(256) void k_qproj(
    const float* __restrict__ bands, const int* __restrict__ sel,
    const float* __restrict__ ipw, const float* __restrict__ ipb,
    float* __restrict__ q)
{
    __shared__ float xs[64][204];
    const int b = blockIdx.x;
    const int t = threadIdx.x;
    const int band = sel[b];
    for (int idx = t; idx < KQN * DM; idx += 256) {
        const int r = idx / DM, col = idx - r * DM;
        xs[r][col] = bands[(size_t)((band * BATCH + b) * KQN + r) * DM + col];
    }
    __syncthreads();
    const int r = t & 31, c = t >> 5;
    for (int oo = c; oo < DM; oo += 8) {
        const float* wrow = ipw + (size_t)oo * DM;   // wq rows 0..199
        const float bias = ipb[oo];
        float4 s0 = {0, 0, 0, 0}, s1 = {0, 0, 0, 0};
        for (int in = 0; in < DM; in += 4) {
            const float4 w4 = *(const float4*)(wrow + in);
            const float4 x0 = *(const float4*)&xs[r][in];
            const float4 x1 = *(const float4*)&xs[r + 32][in];
            s0.x = fmaf(x0.x, w4.x, s0.x); s0.y = fmaf(x0.y, w4.y, s0.y);
            s0.z = fmaf(x0.z, w4.z, s0.z); s0.w = fmaf(x0.w, w4.w, s0.w);
            s1.x = fmaf(x1.x, w4.x, s1.x); s1.y = fmaf(x1.y, w4.y, s1.y);
            s1.z = fmaf(x1.z, w4.z, s1.z); s1.w = fmaf(x1.w, w4.w, s1.w);
        }
        const float a0 = bias + ((s0.x + s0.y) + (s0.z + s0.w));
        const float a1 = bias + ((s1.x + s1.y) + (s1.z + s1.w));
        q[(size_t)(b * KQN + r) * DM + oo] = a0;
        q[(size_t)(b * KQN + r + 32) * DM + oo] = a1;
    }
}

// ---------------------------------------------------------------------------
// K5: kv projection as bf16 MFMA GEMM (unchanged).
// ---------------------------------------------------------------------------
__global__ __launch_bounds__(256) void k_kvproj(
    const float* __restrict__ bands, const unsigned short* __restrict__ Wb,
    const float* __restrict__ ipb, __hip_bfloat16* __restrict__ Kp,
    __hip_bfloat16* __restrict__ Vp)
{
    __shared__ __align__(16) unsigned short Xs[64][KPAD];
    __shared__ __align__(16) unsigned short Ws[80][KPAD];
    __shared__ float Bbias[80];
    const int t  = threadIdx.x;
    const int M0 = blockIdx.x * 64;     // global kv row base
    const int n0 = blockIdx.y * 80;     // output col base (0..400)

    {
        const float4* wsrc = (const float4*)(Wb + (size_t)n0 * KPAD);
        float4* wdst = (float4*)&Ws[0][0];
        for (int i = t; i < 2320; i += 256) wdst[i] = wsrc[i];
    }
    if (t < 80) Bbias[t] = ipb[DM + n0 + t];
    for (int i = t; i < 64 * 50; i += 256) {
        const int r = i / 50, g = i - r * 50;
        const int gg = M0 + r;
        const int bb = gg / TKV, tk = gg - bb * TKV;
        const int band = tk >> 6, kk = tk & 63;
        const float4 x4 = *(const float4*)(bands
            + ((size_t)((band * BATCH + bb) * KQN + kk)) * DM + g * 4);
        ushort4 u;
        u.x = f2bf(x4.x); u.y = f2bf(x4.y); u.z = f2bf(x4.z); u.w = f2bf(x4.w);
        *(ushort4*)&Xs[r][g * 4] = u;
    }
    for (int i = t; i < 64 * 8; i += 256) {
        const int r = i >> 3, g = i & 7;
        ushort4 z; z.x = 0; z.y = 0; z.z = 0; z.w = 0;
        *(ushort4*)&Xs[r][DM + g * 4] = z;
    }
    __syncthreads();

    const int w = t >> 6, lane = t & 63;
    const int lm = lane & 15, quad = lane >> 4;
    const int m0 = w * 16;
    f32x4 acc[5];
#pragma unroll
    for (int nt = 0; nt < 5; ++nt) acc[nt] = (f32x4){0.f, 0.f, 0.f, 0.f};

#pragma unroll
    for (int ks = 0; ks < 7; ++ks) {                 // 7*32 = 224 >= 200
        const int ka = ks * 32 + quad * 8;
        const bf16x8 a = *(const bf16x8*)&Xs[m0 + lm][ka];
#pragma unroll
        for (int nt = 0; nt < 5; ++nt) {
            const bf16x8 bb8 = *(const bf16x8*)&Ws[nt * 16 + lm][ka];
            acc[nt] = __builtin_amdgcn_mfma_f32_16x16x32_bf16(a, bb8, acc[nt], 0, 0, 0);
        }
    }
#pragma unroll
    for (int nt = 0; nt < 5; ++nt) {
        const int col = n0 + nt * 16 + lm;
        const float bias = Bbias[nt * 16 + lm];
#pragma unroll
        for (int reg = 0; reg < 4; ++reg) {
            const int grow = M0 + m0 + quad * 4 + reg;
            const float v = acc[nt][reg] + bias;
            if (col < DM) Kp[(size_t)grow * DM + col] = __float2bfloat16(v);
            else          Vp[(size_t)grow * DM + (col - DM)] = __float2bfloat16(v);
        }
    }
}

// ---------------------------------------------------------------------------
// K6: MFMA attention per (b, head) (unchanged from R3).
// ---------------------------------------------------------------------------
__global__ __launch_bounds__(256) void k_attn(
    const float* __restrict__ qbuf, const __hip_bfloat16* __restrict__ Kp,
    const __hip_bfloat16* __restrict__ Vp, float* __restrict__ obuf)
{
    __shared__ __align__(16) unsigned short Qs[64][72];    // [query][k 0..63]
    __shared__ __align__(16) unsigned short KP[320][72];   // [key][k 0..63]
    __shared__ __align__(16) unsigned short Vt[64][328];   // [e][key]
    __shared__ __align__(16) unsigned short Ps[64][328];   // [query][key]
    const int b = blockIdx.x, hh = blockIdx.y;
    const int t = threadIdx.x;

    for (int idx = t; idx < 64 * 64; idx += 256) {
        const int r = idx >> 6, e = idx & 63;
        const float v = (e < HD) ? qbuf[(size_t)(b * KQN + r) * DM + hh * HD + e] : 0.f;
        Qs[r][e] = f2bf(v);
    }
    const unsigned short* kbase = (const unsigned short*)Kp + (size_t)b * TKV * DM + hh * HD;
    for (int idx = t; idx < 320 * 25; idx += 256) {
        const int key = idx / 25, g = idx - key * 25;
        *(unsigned int*)&KP[key][g * 2] =
            *(const unsigned int*)(kbase + (size_t)key * DM + g * 2);
    }
    for (int idx = t; idx < 320 * 7; idx += 256) {   // zero k-pad [50,64)
        const int key = idx / 7, g = idx - key * 7;
        *(unsigned int*)&KP[key][50 + g * 2] = 0;
    }
    const unsigned short* vbase = (const unsigned short*)Vp + (size_t)b * TKV * DM + hh * HD;
    for (int idx = t; idx < 320 * 25; idx += 256) {
        const int key = idx / 25, g = idx - key * 25;
        const unsigned int v = *(const unsigned int*)(vbase + (size_t)key * DM + g * 2);
        Vt[g * 2][key]     = (unsigned short)(v & 0xffffu);
        Vt[g * 2 + 1][key] = (unsigned short)(v >> 16);
    }
    __syncthreads();

    const int w = t >> 6, lane = t & 63;
    const int lm = lane & 15, quad = lane >> 4;
    const int m0 = w * 16;

    f32x4 s[20];
#pragma unroll
    for (int nt = 0; nt < 20; ++nt) s[nt] = (f32x4){0.f, 0.f, 0.f, 0.f};
#pragma unroll
    for (int ks = 0; ks < 2; ++ks) {
        const int ka = ks * 32 + quad * 8;
        const bf16x8 a = *(const bf16x8*)&Qs[m0 + lm][ka];
#pragma unroll
        for (int nt = 0; nt < 20; ++nt) {
            const bf16x8 bb8 = *(const bf16x8*)&KP[nt * 16 + lm][ka];
            s[nt] = __builtin_amdgcn_mfma_f32_16x16x32_bf16(a, bb8, s[nt], 0, 0, 0);
        }
    }

    const float scale = 0.14142135623730951f;  // 1/sqrt(50)
    float inv[4];
#pragma unroll
    for (int reg = 0; reg < 4; ++reg) {
        float mx = -1e30f;
#pragma unroll
        for (int nt = 0; nt < 20; ++nt) {
            const float sv = s[nt][reg] * scale;
            s[nt][reg] = sv;
            mx = fmaxf(mx, sv);
        }
#pragma unroll
        for (int off = 1; off < 16; off <<= 1)
            mx = fmaxf(mx, __shfl_xor(mx, off, 64));
        float lsum = 0.f;
#pragma unroll
        for (int nt = 0; nt < 20; ++nt) {
            const float p = __expf(s[nt][reg] - mx);
            s[nt][reg] = p;
            lsum += p;
        }
#pragma unroll
        for (int off = 1; off < 16; off <<= 1)
            lsum += __shfl_xor(lsum, off, 64);
        inv[reg] = 1.f / lsum;
    }
#pragma unroll
    for (int reg = 0; reg < 4; ++reg) {
        const int row = m0 + quad * 4 + reg;
#pragma unroll
        for (int nt = 0; nt < 20; ++nt)
            Ps[row][nt * 16 + lm] = f2bf(s[nt][reg]);
    }
    __syncthreads();

    f32x4 o[4];
#pragma unroll
    for (int nt = 0; nt < 4; ++nt) o[nt] = (f32x4){0.f, 0.f, 0.f, 0.f};
#pragma unroll
    for (int ks = 0; ks < 10; ++ks) {
        const int ka = ks * 32 + quad * 8;
        const bf16x8 a = *(const bf16x8*)&Ps[m0 + lm][ka];
#pragma unroll
        for (int nt = 0; nt < 4; ++nt) {
            const bf16x8 bb8 = *(const bf16x8*)&Vt[nt * 16 + lm][ka];
            o[nt] = __builtin_amdgcn_mfma_f32_16x16x32_bf16(a, bb8, o[nt], 0, 0, 0);
        }
    }
    float* op = obuf + (size_t)(b * KQN) * DM + hh * HD;
#pragma unroll
    for (int nt = 0; nt < 4; ++nt) {
        const int e = nt * 16 + lm;
        if (e < HD) {
#pragma unroll
            for (int reg = 0; reg < 4; ++reg) {
                const int row = m0 + quad * 4 + reg;
                op[(size_t)row * DM + e] = o[nt][reg] * inv[reg];
            }
        }
    }
}

// ---------------------------------------------------------------------------
// K7: out = o @ out_w^T + out_b
// ---------------------------------------------------------------------------
__global__ __launch_bounds__(256) void k_outproj(
    const float* __restrict__ obuf, const float* __restrict__ outw,
    const float* __restrict__ outb, float* __restrict__ out)
{
    __shared__ float xs[64][204];
    const int b = blockIdx.x;
    const int t = threadIdx.x;
    for (int idx = t; idx < KQN * DM; idx += 256) {
        const int r = idx / DM, col = idx - r * DM;
        xs[r][col] = obuf[(size_t)(b * KQN + r) * DM + col];
    }
    __syncthreads();
    const int r = t & 31, c = t >> 5;
    for (int oo = c; oo < DM; oo += 8) {
        const float* wrow = outw + (size_t)oo * DM;
        const float bias = outb[oo];
        float4 s0 = {0, 0, 0, 0}, s1 = {0, 0, 0, 0};
        for (int in = 0; in < DM; in += 4) {
            const float4 w4 = *(const float4*)(wrow + in);
            const float4 x0 = *(const float4*)&xs[r][in];
            const float4 x1 = *(const float4*)&xs[r + 32][in];
            s0.x = fmaf(x0.x, w4.x, s0.x); s0.y = fmaf(x0.y, w4.y, s0.y);
            s0.z = fmaf(x0.z, w4.z, s0.z); s0.w = fmaf(x0.w, w4.w, s0.w);
            s1.x = fmaf(x1.x, w4.x, s1.x); s1.y = fmaf(x1.y, w4.y, s1.y);
            s1.z = fmaf(x1.z, w4.z, s1.z); s1.w = fmaf(x1.w, w4.w, s1.w);
        }
        const float a0 = bias + ((s0.x + s0.y) + (s0.z + s0.w));
        const float a1 = bias + ((s1.x + s1.y) + (s1.z + s1.w));
        out[(size_t)(b * KQN + r) * DM + oo] = a0;
        out[(size_t)(b * KQN + r + 32) * DM + oo] = a1;
    }
}

// ---------------------------------------------------------------------------
// Workspace layout (phase-overlapped, peak 183.7 MB < 193 MB):
//   sel  int [512]             @ 0           (2,048)        [live whole run]
//   -- phase 1 (router):
//   wH   bf16 [512][64000]     @ 4096        (65,536,000)
//   wL   bf16 [512][64000]     @ 65,540,096  (65,536,000)
//   part fp32 [8][512][512]    @ 131,076,096 ( 8,388,608)
//   h    fp32 [512][512]       @ 139,464,704 ( 1,048,576)
//   -- phase 2 (attn; overlaps phase-1 bytes, launched after argmax):
//   q    fp32 [512][64][200]   @ 4096        (26,214,400)
//   Wb   bf16 [400][232]       @ 26,218,496  (   185,600)
//   Kp   bf16 [512][320][200]  @ 26,404,096  (65,536,000)
//   Vp   bf16 [512][320][200]  @ 91,940,096  (65,536,000)
//   obuf fp32 [512][64][200]   @ 157,476,096 (26,214,400)  -> ends 183,690,496
// ---------------------------------------------------------------------------
extern "C" void kernel_launch(void* const* d_in, const int* in_sizes, int n_in,
                              void* d_out, int out_size, void* d_ws, size_t ws_size,
                              hipStream_t stream)
{
    const float* bands = (const float*)d_in[0];
    const float* w1    = (const float*)d_in[1];
    const float* b1    = (const float*)d_in[2];
    const float* w2    = (const float*)d_in[3];
    const float* b2    = (const float*)d_in[4];
    const float* ipw   = (const float*)d_in[5];
    const float* ipb   = (const float*)d_in[6];
    const float* outw  = (const float*)d_in[7];
    const float* outb  = (const float*)d_in[8];
    float* out = (float*)d_out;

    if (ws_size < (size_t)192940032) return;

    char* ws = (char*)d_ws;
    int*   sel  = (int*)  (ws + 0);
    unsigned short* wH = (unsigned short*)(ws + 4096);
    unsigned short* wL = (unsigned short*)(ws + 65540096);
    float* part = (float*)(ws + 131076096);
    float* h    = (float*)(ws + 139464704);
    float* q    = (float*)(ws + 4096);                 // phase 2 (wH dead)
    unsigned short* Wb = (unsigned short*)(ws + 26218496);
    __hip_bfloat16* Kp = (__hip_bfloat16*)(ws + 26404096);
    __hip_bfloat16* Vp = (__hip_bfloat16*)(ws + 91940096);
    float* obuf = (float*)(ws + 157476096);

    k_conv_w1<<<FIN * HIDW / 1024, 256, 0, stream>>>(w1, wH, wL);
    k_router_mfma<<<dim3(8, 8, KSPLIT), 256, 0, stream>>>(bands, wH, wL, part);
    k_reduce_relu<<<(BATCH * HIDW) / 256, 256, 0, stream>>>(part, b1, h);
    k_argmax<<<BATCH, 256, 0, stream>>>(h, w2, b2, sel);
    // ---- phase 2: phase-1 buffers (wH/wL/part/h) are dead from here ----
    k_wprep<<<400, 256, 0, stream>>>(ipw, Wb);
    k_qproj<<<BATCH, 256, 0, stream>>>(bands, sel, ipw, ipb, q);
    k_kvproj<<<dim3(2560, 5), 256, 0, stream>>>(bands, Wb, ipb, Kp, Vp);
    k_attn<<<dim3(BATCH, NHEAD), 256, 0, stream>>>(q, Kp, Vp, obuf);
    k_outproj<<<BATCH, 256, 0, stream>>>(obuf, outw, outb, out);
}